// Round 1
// baseline (141.144 us; speedup 1.0000x reference)
//
#include <hip/hip_runtime.h>
#include <math.h>

// Problem constants
// B=4096, SEQ=C=8, L=2048, NK=256, NCLS=100, EBIT=16, EBDIN=4, D=4
// nk enumeration: [0,768) = w3 (n*3+k), [768,1792) = w4, [1792,3072) = w5
// feature rows: K=3 -> n*6+p, K=4 -> 1536+n*5+p, K=5 -> 2816+n*4+p

// Kernel A: for each filter row w_nk (2048 floats) compute the 4 dots with We rows
// and 1 dot with be, then expand over the 128 (h,j) LUT combos into
// R[(h*16+j)*3072 + nk] = relu(sum_d LUT[h,j,d]*WW_d + bw)
__global__ void k_R(const float* __restrict__ We, const float* __restrict__ be,
                    const float* __restrict__ w3, const float* __restrict__ w4,
                    const float* __restrict__ w5, const float* __restrict__ LUT,
                    float* __restrict__ R) {
  int nk = blockIdx.x;  // 0..3071
  const float* wrow;
  if (nk < 768)       wrow = w3 + nk * 2048;
  else if (nk < 1792) wrow = w4 + (nk - 768) * 2048;
  else                wrow = w5 + (nk - 1792) * 2048;
  int t = threadIdx.x;  // 256
  float a0 = 0.f, a1 = 0.f, a2 = 0.f, a3 = 0.f, a4 = 0.f;
  const float4* wp  = (const float4*)wrow;
  const float4* e0p = (const float4*)(We);
  const float4* e1p = (const float4*)(We + 2048);
  const float4* e2p = (const float4*)(We + 4096);
  const float4* e3p = (const float4*)(We + 6144);
  const float4* bep = (const float4*)(be);
  for (int i = t; i < 512; i += 256) {
    float4 w = wp[i];
    float4 e0 = e0p[i], e1 = e1p[i], e2 = e2p[i], e3 = e3p[i], bb = bep[i];
    a0 += w.x * e0.x + w.y * e0.y + w.z * e0.z + w.w * e0.w;
    a1 += w.x * e1.x + w.y * e1.y + w.z * e1.z + w.w * e1.w;
    a2 += w.x * e2.x + w.y * e2.y + w.z * e2.z + w.w * e2.w;
    a3 += w.x * e3.x + w.y * e3.y + w.z * e3.z + w.w * e3.w;
    a4 += w.x * bb.x + w.y * bb.y + w.z * bb.z + w.w * bb.w;
  }
  __shared__ float red[5][256];
  red[0][t] = a0; red[1][t] = a1; red[2][t] = a2; red[3][t] = a3; red[4][t] = a4;
  __syncthreads();
  for (int s = 128; s > 0; s >>= 1) {
    if (t < s) {
      red[0][t] += red[0][t + s];
      red[1][t] += red[1][t + s];
      red[2][t] += red[2][t + s];
      red[3][t] += red[3][t + s];
      red[4][t] += red[4][t + s];
    }
    __syncthreads();
  }
  if (t < 128) {  // t = h*16 + j
    float ww0 = red[0][0], ww1 = red[1][0], ww2 = red[2][0], ww3 = red[3][0];
    float bw = red[4][0];
    const float* lut = LUT + t * 4;
    float v = bw + lut[0] * ww0 + lut[1] * ww1 + lut[2] * ww2 + lut[3] * ww3;
    R[t * 3072 + nk] = fmaxf(v, 0.f);
  }
}

// zero the G table (ws is poisoned 0xAA every launch)
__global__ void k_zeroG(float* __restrict__ G) {
  int i = blockIdx.x * blockDim.x + threadIdx.x;
  if (i < 12800) G[i] = 0.f;
}

// Kernel B: G[h,j,c] += sum over this block's nk-chunk of R[h,j,nk]*W2[row(h,nk),c]
// grid = (8 h, 48 chunks of 64 nk), block = 128 threads (c)
__global__ void k_G(const float* __restrict__ R, const float* __restrict__ W2,
                    float* __restrict__ G) {
  int h = blockIdx.x;
  int z = blockIdx.y;
  int c = threadIdx.x;
  int nk0 = z * 64;
  int K, P, rowbase, n, k;
  if (nk0 < 768)       { K = 3; P = 6; rowbase = 0;    n = nk0 / 3;  k = nk0 - n * 3; }
  else if (nk0 < 1792) { K = 4; P = 5; rowbase = 1536; int t2 = nk0 - 768;  n = t2 >> 2; k = t2 & 3; }
  else                 { K = 5; P = 4; rowbase = 2816; int t2 = nk0 - 1792; n = t2 / 5;  k = t2 - n * 5; }
  float acc[16];
#pragma unroll
  for (int j = 0; j < 16; j++) acc[j] = 0.f;
  bool act = c < 100;
  for (int it = 0; it < 64; ++it) {
    int nk = nk0 + it;
    int p = h - k;
    if (p >= 0 && p < P) {
      float w2v = act ? W2[(rowbase + n * P + p) * 100 + c] : 0.f;
      const float* Rp = R + h * 16 * 3072 + nk;
#pragma unroll
      for (int j = 0; j < 16; j++) acc[j] += Rp[j * 3072] * w2v;
    }
    if (++k == K) { k = 0; ++n; }
  }
  if (act) {
#pragma unroll
    for (int j = 0; j < 16; j++) atomicAdd(&G[(h * 16 + j) * 100 + c], acc[j]);
  }
}

// Kernel C: j*(b,h) = argmax_j ( (sign(m) @ H)[j] ), one thread per (b,h)
__global__ void k_jtab(const int* __restrict__ x, const float* __restrict__ len_emb,
                       const float* __restrict__ ipd_emb, const float* __restrict__ W1,
                       const float* __restrict__ b1, const float* __restrict__ S,
                       const float* __restrict__ Hm, const float* __restrict__ T,
                       int* __restrict__ jtab) {
  int bh = blockIdx.x * blockDim.x + threadIdx.x;
  if (bh >= 32768) return;
  int pos = bh & 7;
  // detect int64 vs int32 x: if passed as int64 (values < 256), all high words are 0.
  bool is64 = true;
#pragma unroll
  for (int q = 0; q < 16; q++) is64 = is64 && (x[2 * q + 1] == 0);
  int i0, i1;
  if (is64) { i0 = x[4 * bh];     i1 = x[4 * bh + 2]; }
  else      { i0 = x[2 * bh];     i1 = x[2 * bh + 1]; }
  const float* le = len_emb + i0 * 16;
  const float* ie = ipd_emb + i1 * 16;
  float hv[4];
#pragma unroll
  for (int d = 0; d < 4; d++) hv[d] = b1[d];
  for (int i = 0; i < 16; i++) {
    float lv = le[i], iv = ie[i];
#pragma unroll
    for (int d = 0; d < 4; d++) hv[d] += lv * W1[i * 4 + d] + iv * W1[(16 + i) * 4 + d];
  }
  float sg[15];
#pragma unroll
  for (int kk = 0; kk < 15; kk++) {
    float m = -1e-4f - T[pos * 15 + kk];
#pragma unroll
    for (int d = 0; d < 4; d++) m += hv[d] * S[(pos * 4 + d) * 15 + kk];
    sg[kk] = (m > 0.f) ? 1.f : ((m < 0.f) ? -1.f : 0.f);
  }
  int bj = 0;
  float bv = -INFINITY;
  for (int j = 0; j < 16; j++) {
    float v = 0.f;
#pragma unroll
    for (int kk = 0; kk < 15; kk++) v += sg[kk] * Hm[kk * 16 + j];
    if (v > bv) { bv = v; bj = j; }  // strict > keeps first max (jnp.argmax semantics)
  }
  jtab[bh] = bj;
}

// Kernel D: logits[b,c] = b2[c] + sum_h G[h, j*(b,h), c]; out = log_softmax
// one 64-thread wave per b; thread t covers c = t and c = t+64
__global__ void k_out(const int* __restrict__ jtab, const float* __restrict__ G,
                      const float* __restrict__ b2, float* __restrict__ out) {
  int b = blockIdx.x;
  int t = threadIdx.x;  // 64
  int js[8];
#pragma unroll
  for (int p = 0; p < 8; p++) js[p] = jtab[b * 8 + p];
  int c0 = t, c1 = t + 64;
  float v0, v1 = -INFINITY;
  {
    float a = b2[c0];
#pragma unroll
    for (int p = 0; p < 8; p++) a += G[(p * 16 + js[p]) * 100 + c0];
    v0 = a;
  }
  if (c1 < 100) {
    float a = b2[c1];
#pragma unroll
    for (int p = 0; p < 8; p++) a += G[(p * 16 + js[p]) * 100 + c1];
    v1 = a;
  }
  float mx = fmaxf(v0, v1);
#pragma unroll
  for (int off = 32; off > 0; off >>= 1) mx = fmaxf(mx, __shfl_xor(mx, off, 64));
  float e = expf(v0 - mx) + ((c1 < 100) ? expf(v1 - mx) : 0.f);
#pragma unroll
  for (int off = 32; off > 0; off >>= 1) e += __shfl_xor(e, off, 64);
  float lse = mx + logf(e);
  out[b * 100 + c0] = v0 - lse;
  if (c1 < 100) out[b * 100 + c1] = v1 - lse;
}

extern "C" void kernel_launch(void* const* d_in, const int* in_sizes, int n_in,
                              void* d_out, int out_size, void* d_ws, size_t ws_size,
                              hipStream_t stream) {
  const int*   x       = (const int*)  d_in[0];
  const float* len_emb = (const float*)d_in[1];
  const float* ipd_emb = (const float*)d_in[2];
  const float* W1      = (const float*)d_in[3];
  const float* b1      = (const float*)d_in[4];
  const float* We      = (const float*)d_in[5];
  const float* be      = (const float*)d_in[6];
  const float* w3      = (const float*)d_in[7];
  const float* w4      = (const float*)d_in[8];
  const float* w5      = (const float*)d_in[9];
  const float* W2      = (const float*)d_in[10];
  const float* b2      = (const float*)d_in[11];
  const float* S       = (const float*)d_in[12];
  const float* Hm      = (const float*)d_in[13];
  const float* T       = (const float*)d_in[14];
  const float* LUT     = (const float*)d_in[15];
  float* out = (float*)d_out;

  // scratch: R (128*3072 f32 = 1.5 MB) lives in d_out (1.6375 MB) — it is dead
  // before k_out overwrites d_out. G (51200 B) + jtab (131072 B) live in ws.
  float* R    = (float*)d_out;
  float* G    = (float*)d_ws;
  int*   jtab = (int*)((char*)d_ws + 51200);

  k_zeroG<<<13, 1024, 0, stream>>>(G);
  k_R<<<3072, 256, 0, stream>>>(We, be, w3, w4, w5, LUT, R);
  k_jtab<<<128, 256, 0, stream>>>(x, len_emb, ipd_emb, W1, b1, S, Hm, T, jtab);
  dim3 gB(8, 48);
  k_G<<<gB, 128, 0, stream>>>(R, W2, G);
  k_out<<<4096, 64, 0, stream>>>(jtab, G, b2, out);
}

// Round 2
// 138.659 us; speedup vs baseline: 1.0179x; 1.0179x over previous
//
#include <hip/hip_runtime.h>
#include <math.h>

// Problem constants
// B=4096, SEQ=C=8, L=2048, NK=256, NCLS=100, EBIT=16, EBDIN=4, D=4
// nk enumeration: [0,768) = w3 (n*3+k), [768,1792) = w4, [1792,3072) = w5
// feature rows: K=3 -> n*6+p, K=4 -> 1536+n*5+p, K=5 -> 2816+n*4+p

// Kernel 1: one wave per nk. Butterfly-reduce the 5 dots (w_nk . We_d, w_nk . be),
// then expand over the 128 (h,j) LUT combos into R[(h*16+j)*3072 + nk].
// Block 0 additionally zero-inits G (ws is poisoned 0xAA each launch).
__global__ void k_Rz(const float* __restrict__ We, const float* __restrict__ be,
                     const float* __restrict__ w3, const float* __restrict__ w4,
                     const float* __restrict__ w5, const float* __restrict__ LUT,
                     float* __restrict__ R, float* __restrict__ G) {
  int tid = threadIdx.x;            // 256 = 4 waves
  if (blockIdx.x == 0) {
    for (int i = tid; i < 12800; i += 256) G[i] = 0.f;
  }
  int lane = tid & 63;
  int nk = blockIdx.x * 4 + (tid >> 6);   // 0..3071
  const float* wrow;
  if (nk < 768)       wrow = w3 + nk * 2048;
  else if (nk < 1792) wrow = w4 + (nk - 768) * 2048;
  else                wrow = w5 + (nk - 1792) * 2048;
  float a0 = 0.f, a1 = 0.f, a2 = 0.f, a3 = 0.f, a4 = 0.f;
  const float4* wp  = (const float4*)wrow;
  const float4* e0p = (const float4*)(We);
  const float4* e1p = (const float4*)(We + 2048);
  const float4* e2p = (const float4*)(We + 4096);
  const float4* e3p = (const float4*)(We + 6144);
  const float4* bep = (const float4*)(be);
#pragma unroll
  for (int i = lane; i < 512; i += 64) {
    float4 w = wp[i];
    float4 e0 = e0p[i], e1 = e1p[i], e2 = e2p[i], e3 = e3p[i], bb = bep[i];
    a0 += w.x * e0.x + w.y * e0.y + w.z * e0.z + w.w * e0.w;
    a1 += w.x * e1.x + w.y * e1.y + w.z * e1.z + w.w * e1.w;
    a2 += w.x * e2.x + w.y * e2.y + w.z * e2.z + w.w * e2.w;
    a3 += w.x * e3.x + w.y * e3.y + w.z * e3.z + w.w * e3.w;
    a4 += w.x * bb.x + w.y * bb.y + w.z * bb.z + w.w * bb.w;
  }
#pragma unroll
  for (int off = 32; off > 0; off >>= 1) {
    a0 += __shfl_xor(a0, off, 64);
    a1 += __shfl_xor(a1, off, 64);
    a2 += __shfl_xor(a2, off, 64);
    a3 += __shfl_xor(a3, off, 64);
    a4 += __shfl_xor(a4, off, 64);
  }
  // all lanes now hold the full sums; lanes cover the 128 (h,j) combos, 2 each
#pragma unroll
  for (int r = 0; r < 2; r++) {
    int rr = lane + r * 64;       // h*16+j
    const float* lut = LUT + rr * 4;
    float v = a4 + lut[0] * a0 + lut[1] * a1 + lut[2] * a2 + lut[3] * a3;
    R[rr * 3072 + nk] = fmaxf(v, 0.f);
  }
}

// Kernel 2: G[h,j,c] += sum over this block's nk-chunk of R[h,j,nk]*W2[row(h,nk),c]
// grid = (8 h, 48 chunks of 64 nk), block = 128 threads (c)
__global__ void k_G(const float* __restrict__ R, const float* __restrict__ W2,
                    float* __restrict__ G) {
  int h = blockIdx.x;
  int z = blockIdx.y;
  int c = threadIdx.x;
  int nk0 = z * 64;
  int K, P, rowbase, n, k;
  if (nk0 < 768)       { K = 3; P = 6; rowbase = 0;    n = nk0 / 3;  k = nk0 - n * 3; }
  else if (nk0 < 1792) { K = 4; P = 5; rowbase = 1536; int t2 = nk0 - 768;  n = t2 >> 2; k = t2 & 3; }
  else                 { K = 5; P = 4; rowbase = 2816; int t2 = nk0 - 1792; n = t2 / 5;  k = t2 - n * 5; }
  float acc[16];
#pragma unroll
  for (int j = 0; j < 16; j++) acc[j] = 0.f;
  bool act = c < 100;
  for (int it = 0; it < 64; ++it) {
    int nk = nk0 + it;
    int p = h - k;
    if (p >= 0 && p < P) {
      float w2v = act ? W2[(rowbase + n * P + p) * 100 + c] : 0.f;
      const float* Rp = R + h * 16 * 3072 + nk;
#pragma unroll
      for (int j = 0; j < 16; j++) acc[j] += Rp[j * 3072] * w2v;
    }
    if (++k == K) { k = 0; ++n; }
  }
  if (act) {
#pragma unroll
    for (int j = 0; j < 16; j++) atomicAdd(&G[(h * 16 + j) * 100 + c], acc[j]);
  }
}

// Kernel 3: per b, threads 0..7 compute j*(b,h) = argmax_j((sign(m) @ H)[j]);
// then logits[b,c] = b2[c] + sum_h G[h, j*(b,h), c]; out = log_softmax.
__global__ void k_out(const int* __restrict__ x, const float* __restrict__ len_emb,
                      const float* __restrict__ ipd_emb, const float* __restrict__ W1,
                      const float* __restrict__ b1, const float* __restrict__ S,
                      const float* __restrict__ Hm, const float* __restrict__ T,
                      const float* __restrict__ G, const float* __restrict__ b2,
                      float* __restrict__ out) {
  int b = blockIdx.x;
  int t = threadIdx.x;  // 64 = 1 wave
  __shared__ int js[8];
  if (t < 8) {
    int pos = t;
    int bh = b * 8 + pos;
    // detect int64 vs int32 x: if int64 (values < 256), all high words are 0
    bool is64 = true;
#pragma unroll
    for (int q = 0; q < 16; q++) is64 = is64 && (x[2 * q + 1] == 0);
    int i0, i1;
    if (is64) { i0 = x[4 * bh]; i1 = x[4 * bh + 2]; }
    else      { i0 = x[2 * bh]; i1 = x[2 * bh + 1]; }
    const float* le = len_emb + i0 * 16;
    const float* ie = ipd_emb + i1 * 16;
    float hv[4];
#pragma unroll
    for (int d = 0; d < 4; d++) hv[d] = b1[d];
    for (int i = 0; i < 16; i++) {
      float lv = le[i], iv = ie[i];
#pragma unroll
      for (int d = 0; d < 4; d++) hv[d] += lv * W1[i * 4 + d] + iv * W1[(16 + i) * 4 + d];
    }
    float sg[15];
#pragma unroll
    for (int kk = 0; kk < 15; kk++) {
      float m = -1e-4f - T[pos * 15 + kk];
#pragma unroll
      for (int d = 0; d < 4; d++) m += hv[d] * S[(pos * 4 + d) * 15 + kk];
      sg[kk] = (m > 0.f) ? 1.f : ((m < 0.f) ? -1.f : 0.f);
    }
    int bj = 0;
    float bv = -INFINITY;
    for (int j = 0; j < 16; j++) {
      float v = 0.f;
#pragma unroll
      for (int kk = 0; kk < 15; kk++) v += sg[kk] * Hm[kk * 16 + j];
      if (v > bv) { bv = v; bj = j; }  // strict > keeps first max (jnp.argmax)
    }
    js[pos] = bj;
  }
  __syncthreads();
  int c0 = t, c1 = t + 64;
  float v0, v1 = -INFINITY;
  {
    float a = b2[c0];
#pragma unroll
    for (int p = 0; p < 8; p++) a += G[(p * 16 + js[p]) * 100 + c0];
    v0 = a;
  }
  if (c1 < 100) {
    float a = b2[c1];
#pragma unroll
    for (int p = 0; p < 8; p++) a += G[(p * 16 + js[p]) * 100 + c1];
    v1 = a;
  }
  float mx = fmaxf(v0, v1);
#pragma unroll
  for (int off = 32; off > 0; off >>= 1) mx = fmaxf(mx, __shfl_xor(mx, off, 64));
  float e = expf(v0 - mx) + ((c1 < 100) ? expf(v1 - mx) : 0.f);
#pragma unroll
  for (int off = 32; off > 0; off >>= 1) e += __shfl_xor(e, off, 64);
  float lse = mx + logf(e);
  out[b * 100 + c0] = v0 - lse;
  if (c1 < 100) out[b * 100 + c1] = v1 - lse;
}

extern "C" void kernel_launch(void* const* d_in, const int* in_sizes, int n_in,
                              void* d_out, int out_size, void* d_ws, size_t ws_size,
                              hipStream_t stream) {
  const int*   x       = (const int*)  d_in[0];
  const float* len_emb = (const float*)d_in[1];
  const float* ipd_emb = (const float*)d_in[2];
  const float* W1      = (const float*)d_in[3];
  const float* b1      = (const float*)d_in[4];
  const float* We      = (const float*)d_in[5];
  const float* be      = (const float*)d_in[6];
  const float* w3      = (const float*)d_in[7];
  const float* w4      = (const float*)d_in[8];
  const float* w5      = (const float*)d_in[9];
  const float* W2      = (const float*)d_in[10];
  const float* b2      = (const float*)d_in[11];
  const float* S       = (const float*)d_in[12];
  const float* Hm      = (const float*)d_in[13];
  const float* T       = (const float*)d_in[14];
  const float* LUT     = (const float*)d_in[15];
  float* out = (float*)d_out;

  // R (128*3072 f32 = 1.5 MB) lives in d_out (dead before k_out overwrites it).
  // G (12800 f32 = 51200 B) lives at the start of ws.
  float* R = (float*)d_out;
  float* G = (float*)d_ws;

  k_Rz<<<768, 256, 0, stream>>>(We, be, w3, w4, w5, LUT, R, G);
  dim3 gB(8, 48);
  k_G<<<gB, 128, 0, stream>>>(R, W2, G);
  k_out<<<4096, 64, 0, stream>>>(x, len_emb, ipd_emb, W1, b1, S, Hm, T, G, b2, out);
}

// Round 3
// 137.920 us; speedup vs baseline: 1.0234x; 1.0054x over previous
//
#include <hip/hip_runtime.h>
#include <math.h>

// Problem constants
// B=4096, SEQ=C=8, L=2048, NK=256, NCLS=100, EBIT=16, EBDIN=4, D=4
// nk enumeration: [0,768) = w3 (n*3+k), [768,1792) = w4, [1792,3072) = w5
// feature rows: K=3 -> n*6+p, K=4 -> 1536+n*5+p, K=5 -> 2816+n*4+p

// Kernel 1: one wave per nk. Butterfly-reduce the 5 dots (w_nk . We_d, w_nk . be),
// then expand over the 128 (h,j) LUT combos into R[(h*16+j)*3072 + nk].
// Block 0 additionally zero-inits G (ws is poisoned 0xAA each launch).
__global__ void k_Rz(const float* __restrict__ We, const float* __restrict__ be,
                     const float* __restrict__ w3, const float* __restrict__ w4,
                     const float* __restrict__ w5, const float* __restrict__ LUT,
                     float* __restrict__ R, float* __restrict__ G) {
  int tid = threadIdx.x;            // 256 = 4 waves
  if (blockIdx.x == 0) {
    for (int i = tid; i < 12800; i += 256) G[i] = 0.f;
  }
  int lane = tid & 63;
  int nk = blockIdx.x * 4 + (tid >> 6);   // 0..3071
  const float* wrow;
  if (nk < 768)       wrow = w3 + nk * 2048;
  else if (nk < 1792) wrow = w4 + (nk - 768) * 2048;
  else                wrow = w5 + (nk - 1792) * 2048;
  float a0 = 0.f, a1 = 0.f, a2 = 0.f, a3 = 0.f, a4 = 0.f;
  const float4* wp  = (const float4*)wrow;
  const float4* e0p = (const float4*)(We);
  const float4* e1p = (const float4*)(We + 2048);
  const float4* e2p = (const float4*)(We + 4096);
  const float4* e3p = (const float4*)(We + 6144);
  const float4* bep = (const float4*)(be);
#pragma unroll
  for (int i = lane; i < 512; i += 64) {
    float4 w = wp[i];
    float4 e0 = e0p[i], e1 = e1p[i], e2 = e2p[i], e3 = e3p[i], bb = bep[i];
    a0 += w.x * e0.x + w.y * e0.y + w.z * e0.z + w.w * e0.w;
    a1 += w.x * e1.x + w.y * e1.y + w.z * e1.z + w.w * e1.w;
    a2 += w.x * e2.x + w.y * e2.y + w.z * e2.z + w.w * e2.w;
    a3 += w.x * e3.x + w.y * e3.y + w.z * e3.z + w.w * e3.w;
    a4 += w.x * bb.x + w.y * bb.y + w.z * bb.z + w.w * bb.w;
  }
#pragma unroll
  for (int off = 32; off > 0; off >>= 1) {
    a0 += __shfl_xor(a0, off, 64);
    a1 += __shfl_xor(a1, off, 64);
    a2 += __shfl_xor(a2, off, 64);
    a3 += __shfl_xor(a3, off, 64);
    a4 += __shfl_xor(a4, off, 64);
  }
  // all lanes now hold the full sums; lanes cover the 128 (h,j) combos, 2 each
#pragma unroll
  for (int r = 0; r < 2; r++) {
    int rr = lane + r * 64;       // h*16+j
    const float* lut = LUT + rr * 4;
    float v = a4 + lut[0] * a0 + lut[1] * a1 + lut[2] * a2 + lut[3] * a3;
    R[rr * 3072 + nk] = fmaxf(v, 0.f);
  }
}

// Kernel 2: G[h,j,c] += sum over this block's nk-chunk of R[h,j,nk]*W2[row(h,nk),c]
// grid = (8 h, 48 chunks of 64 nk), block = 128 threads (c).
// Fully unrolled it-loop so the 64 independent w2v loads pipeline (MLP) instead
// of forming a serial load->use chain.
__global__ void k_G(const float* __restrict__ R, const float* __restrict__ W2,
                    float* __restrict__ G) {
  int h = blockIdx.x;
  int z = blockIdx.y;
  int c = threadIdx.x;
  int nk0 = z * 64;
  int K, P, rowbase, n0, k0;
  if (nk0 < 768)       { K = 3; P = 6; rowbase = 0;    n0 = nk0 / 3;  k0 = nk0 - n0 * 3; }
  else if (nk0 < 1792) { K = 4; P = 5; rowbase = 1536; int t2 = nk0 - 768;  n0 = t2 >> 2; k0 = t2 & 3; }
  else                 { K = 5; P = 4; rowbase = 2816; int t2 = nk0 - 1792; n0 = t2 / 5;  k0 = t2 - n0 * 5; }
  float acc[16];
#pragma unroll
  for (int j = 0; j < 16; j++) acc[j] = 0.f;
  bool act = c < 100;
  const float* Rh = R + h * 16 * 3072;
  int n = n0, k = k0;
#pragma unroll
  for (int it = 0; it < 64; ++it) {
    int nk = nk0 + it;
    int p = h - k;
    if (p >= 0 && p < P) {
      float w2v = act ? W2[(rowbase + n * P + p) * 100 + c] : 0.f;
      const float* Rp = Rh + nk;
#pragma unroll
      for (int j = 0; j < 16; j++) acc[j] += Rp[j * 3072] * w2v;
    }
    if (++k == K) { k = 0; ++n; }
  }
  if (act) {
#pragma unroll
    for (int j = 0; j < 16; j++) atomicAdd(&G[(h * 16 + j) * 100 + c], acc[j]);
  }
}

// Kernel 3: 256 threads = 4 waves, one wave per b (grid 1024).
// Lanes 0..7 of each wave compute j*(b,h) = argmax_j((sign(m) @ H)[j]);
// broadcast via __shfl (no LDS/barrier). Then logits + log_softmax.
__global__ void k_out(const int* __restrict__ x, const float* __restrict__ len_emb,
                      const float* __restrict__ ipd_emb, const float* __restrict__ W1,
                      const float* __restrict__ b1, const float* __restrict__ S,
                      const float* __restrict__ Hm, const float* __restrict__ T,
                      const float* __restrict__ G, const float* __restrict__ b2,
                      float* __restrict__ out) {
  int b = blockIdx.x * 4 + (threadIdx.x >> 6);
  int t = threadIdx.x & 63;  // lane within wave
  int bj = 0;
  if (t < 8) {
    int pos = t;
    int bh = b * 8 + pos;
    // detect int64 vs int32 x: if int64 (values < 256), all high words are 0
    bool is64 = true;
#pragma unroll
    for (int q = 0; q < 16; q++) is64 = is64 && (x[2 * q + 1] == 0);
    int i0, i1;
    if (is64) { i0 = x[4 * bh]; i1 = x[4 * bh + 2]; }
    else      { i0 = x[2 * bh]; i1 = x[2 * bh + 1]; }
    const float* le = len_emb + i0 * 16;
    const float* ie = ipd_emb + i1 * 16;
    float hv[4];
#pragma unroll
    for (int d = 0; d < 4; d++) hv[d] = b1[d];
    for (int i = 0; i < 16; i++) {
      float lv = le[i], iv = ie[i];
#pragma unroll
      for (int d = 0; d < 4; d++) hv[d] += lv * W1[i * 4 + d] + iv * W1[(16 + i) * 4 + d];
    }
    float sg[15];
#pragma unroll
    for (int kk = 0; kk < 15; kk++) {
      float m = -1e-4f - T[pos * 15 + kk];
#pragma unroll
      for (int d = 0; d < 4; d++) m += hv[d] * S[(pos * 4 + d) * 15 + kk];
      sg[kk] = (m > 0.f) ? 1.f : ((m < 0.f) ? -1.f : 0.f);
    }
    float bv = -INFINITY;
    for (int j = 0; j < 16; j++) {
      float v = 0.f;
#pragma unroll
      for (int kk = 0; kk < 15; kk++) v += sg[kk] * Hm[kk * 16 + j];
      if (v > bv) { bv = v; bj = j; }  // strict > keeps first max (jnp.argmax)
    }
  }
  int js[8];
#pragma unroll
  for (int p = 0; p < 8; p++) js[p] = __shfl(bj, p, 64);
  int c0 = t, c1 = t + 64;
  float v0, v1 = -INFINITY;
  {
    float a = b2[c0];
#pragma unroll
    for (int p = 0; p < 8; p++) a += G[(p * 16 + js[p]) * 100 + c0];
    v0 = a;
  }
  if (c1 < 100) {
    float a = b2[c1];
#pragma unroll
    for (int p = 0; p < 8; p++) a += G[(p * 16 + js[p]) * 100 + c1];
    v1 = a;
  }
  float mx = fmaxf(v0, v1);
#pragma unroll
  for (int off = 32; off > 0; off >>= 1) mx = fmaxf(mx, __shfl_xor(mx, off, 64));
  float e = expf(v0 - mx) + ((c1 < 100) ? expf(v1 - mx) : 0.f);
#pragma unroll
  for (int off = 32; off > 0; off >>= 1) e += __shfl_xor(e, off, 64);
  float lse = mx + logf(e);
  out[b * 100 + c0] = v0 - lse;
  if (c1 < 100) out[b * 100 + c1] = v1 - lse;
}

extern "C" void kernel_launch(void* const* d_in, const int* in_sizes, int n_in,
                              void* d_out, int out_size, void* d_ws, size_t ws_size,
                              hipStream_t stream) {
  const int*   x       = (const int*)  d_in[0];
  const float* len_emb = (const float*)d_in[1];
  const float* ipd_emb = (const float*)d_in[2];
  const float* W1      = (const float*)d_in[3];
  const float* b1      = (const float*)d_in[4];
  const float* We      = (const float*)d_in[5];
  const float* be      = (const float*)d_in[6];
  const float* w3      = (const float*)d_in[7];
  const float* w4      = (const float*)d_in[8];
  const float* w5      = (const float*)d_in[9];
  const float* W2      = (const float*)d_in[10];
  const float* b2      = (const float*)d_in[11];
  const float* S       = (const float*)d_in[12];
  const float* Hm      = (const float*)d_in[13];
  const float* T       = (const float*)d_in[14];
  const float* LUT     = (const float*)d_in[15];
  float* out = (float*)d_out;

  // R (128*3072 f32 = 1.5 MB) lives in d_out (dead before k_out overwrites it).
  // G (12800 f32 = 51200 B) lives at the start of ws.
  float* R = (float*)d_out;
  float* G = (float*)d_ws;

  k_Rz<<<768, 256, 0, stream>>>(We, be, w3, w4, w5, LUT, R, G);
  dim3 gB(8, 48);
  k_G<<<gB, 128, 0, stream>>>(R, W2, G);
  k_out<<<1024, 256, 0, stream>>>(x, len_emb, ipd_emb, W1, b1, S, Hm, T, G, b2, out);
}